// Round 11
// baseline (217.282 us; speedup 1.0000x reference)
//
#include <hip/hip_runtime.h>
#include <math.h>

typedef float v2f __attribute__((ext_vector_type(2)));

#define NX 256
#define NY 256
#define N_STEPS 300
#define N_CELLS (NX * NY)
#define TILE_R 8             // tile rows per block
#define TILE_C 16            // tile cols per block
#define HALO 8
#define RROWS 24             // region rows = TILE_R + 2*HALO
#define LSTR 36              // LDS row stride in floats
#define LROWS 26             // region rows + pad row each side
#define LIDX(rr, cc) (((rr) + 1) * LSTR + ((cc) + 2))
#define NBX 16               // tile-grid cols (256/TILE_C)
#define NBY 32               // tile-grid rows (256/TILE_R)
#define NBLKS (NBX * NBY)    // 512 blocks -> 2 per CU
#define NTHREADS 384         // 24 rows x 16 col-pairs
#define NCHUNK 38            // 38*8 = 304 >= 300; history suppressed past 299

// f32 constants (double-precision fold -> f32)
#define kINV_DX       1280.0f
#define kINV_DY       1280.0f
#define kDT           2.5e-5f
#define kMU           25000.0f
#define kETA          0.1f
#define kDT_OVER_RHO  2.5e-8f
#define kONE_MINUS_BD 0.99999975f
#define kNEG_INV_2SIG2 (-55555.5546875f)   // -1/(2*0.003^2)
#define kDX           7.8125e-4f
#define kEPS          1e-8f
#define kSRC_SKIP_D2  9.0e-4f              // (0.03 m)^2: exp(-55555*9e-4) ~ 2e-22

__device__ __forceinline__ float dprof(int k) {
    int m = min(k, NX - 1 - k);
    if (m >= 20) return 1.0f;
    float arg = 3.14159265358979f * (float)(20 - m) / 20.0f;
    return 1.0f - 0.05f * (0.5f + 0.5f * cosf(arg));
}

// LLC-coherent (agent-scope, relaxed) accessors — no cache-maintenance ops.
__device__ __forceinline__ void st_f2(float* p, v2f v) {
    union { v2f f; unsigned long long u; } x;
    x.f = v;
    __hip_atomic_store((unsigned long long*)p, x.u,
                       __ATOMIC_RELAXED, __HIP_MEMORY_SCOPE_AGENT);
}
__device__ __forceinline__ v2f ld_f2(const float* p) {
    union { unsigned long long u; v2f f; } x;
    x.u = __hip_atomic_load((const unsigned long long*)p,
                            __ATOMIC_RELAXED, __HIP_MEMORY_SCOPE_AGENT);
    return x.f;
}
__device__ __forceinline__ float ld_f1(const float* p) {
    union { unsigned u; float f; } x;
    x.u = __hip_atomic_load((const unsigned*)p,
                            __ATOMIC_RELAXED, __HIP_MEMORY_SCOPE_AGENT);
    return x.f;
}

// Plain (non-cooperative) launch: our sync is hand-rolled neighbor flags, so
// we need actual co-residency, not the cooperative API's validation (which
// silently rejected 512 blocks in R10). __launch_bounds__(384, 3): 3 waves/EU
// = 12 waves/CU = 2 blocks/CU guaranteed register-schedulable; LDS 7.5KB and
// VGPR ~44 leave capacity >= 5 blocks/CU, so greedy dispatch places all 512.
__global__ __launch_bounds__(NTHREADS, 3) void persist_kernel(
    const float2* __restrict__ traj,
    float* __restrict__ out,
    float* __restrict__ ws,
    unsigned* __restrict__ seq)      // per-block flags, stride 4 uints
{
    __shared__ float s_vz[2][LROWS * LSTR];

    float* vzS[2]  = { ws + 0 * N_CELLS, ws + 1 * N_CELLS };
    float* sxzS[2] = { ws + 2 * N_CELLS, ws + 3 * N_CELLS };
    float* syzS[2] = { ws + 4 * N_CELLS, ws + 5 * N_CELLS };

    const int tid = threadIdx.x;
    const int bid = blockIdx.x;
    const int bx  = bid & (NBX - 1), by = bid >> 4;
    const int r   = tid >> 4;            // region row, 0..23
    const int c0  = (tid & 15) << 1;     // region col base, 0,2,...,30

    const int gi  = by * TILE_R + r  - HALO;
    const int gj0 = bx * TILE_C + c0 - HALO;
    const int g   = gi * NY + gj0;

    const bool rowOK  = (gi >= 0) && (gi < NX);
    const bool colOK  = (gj0 >= 0) && (gj0 < NY);
    const bool inD    = rowOK && colOK;
    const bool haloUp   = (gi - 1 >= 0) && (gi - 1 < NX) && colOK;
    const bool haloLeft = rowOK && (gj0 - 1 >= 0);

    // boundary handling as premultiplied masks (mul-by-0 == reference zero pad)
    const float mxF  = (gi < NX - 1)      ? kINV_DX : 0.0f;
    const float myF1 = (gj0 + 1 < NY - 1) ? kINV_DY : 0.0f;
    const float mbX  = (gi > 0)           ? kINV_DX : 0.0f;
    const float mbY0 = (gj0 > 0)          ? kINV_DY : 0.0f;
    const v2f mx2  = {mxF, mxF};
    const v2f my2  = {kINV_DY, myF1};
    const v2f mbx2 = {mbX, mbX};
    const v2f mby2 = {mbY0, kINV_DY};

    const float dpx = rowOK ? dprof(gi) : 0.0f;
    const v2f damp2 = { inD ? dpx * dprof(gj0) * kONE_MINUS_BD : 0.0f,
                        inD ? dpx * dprof(gj0 + 1) * kONE_MINUS_BD : 0.0f };
    const float xi  = ((float)gi + 0.5f) * kDX;
    const v2f   yy2 = { ((float)gj0 + 0.5f) * kDX, ((float)gj0 + 1.5f) * kDX };

    const bool owned = (r >= HALO) && (r < HALO + TILE_R) &&
                       (c0 >= HALO) && (c0 + 1 < HALO + TILE_C);

    // region bbox in meters (x = rows/by, y = cols/bx) for source-skip test
    const float xlo = ((float)(by * TILE_R - HALO) + 0.5f) * kDX;
    const float xhi = ((float)(by * TILE_R + TILE_R + HALO - 1) + 0.5f) * kDX;
    const float ylo = ((float)(bx * TILE_C - HALO) + 0.5f) * kDX;
    const float yhi = ((float)(bx * TILE_C + TILE_C + HALO - 1) + 0.5f) * kDX;

    // poller lanes: first 8 threads each own one neighbor direction
    bool isPoller = false; int pollIdx = 0;
    if (tid < 8) {
        const int q  = tid + (tid >= 4);     // skip center of 3x3
        const int dy = q / 3 - 1, dx = q % 3 - 1;
        const int nbx_ = bx + dx, nby_ = by + dy;
        if (nbx_ >= 0 && nbx_ < NBX && nby_ >= 0 && nby_ < NBY) {
            isPoller = true;
            pollIdx = (nby_ * NBX + nbx_) * 4;
        }
    }

    // zero LDS once; pads stay zero forever
    for (int idx = tid; idx < 2 * LROWS * LSTR; idx += NTHREADS)
        ((float*)s_vz)[idx] = 0.0f;

    // persistent per-thread state
    v2f V = {0.f, 0.f}, SX = {0.f, 0.f}, SY = {0.f, 0.f}, SXM = {0.f, 0.f};
    float symv = 0.f;
    __syncthreads();

    for (int ch = 0; ch < NCHUNK; ++ch) {
        if (ch > 0) {
            // wait: all existing neighbors completed chunk ch-1 (flag >= ch)
            if (isPoller) {
                const unsigned tgt = (unsigned)ch;
                while (__hip_atomic_load(&seq[pollIdx], __ATOMIC_RELAXED,
                                         __HIP_MEMORY_SCOPE_AGENT) < tgt) {
                    __builtin_amdgcn_s_sleep(1);
                }
            }
            __syncthreads();   // poll done for all 8 dirs before anyone reads

            // halo-only reload (LLC-coherent loads; owners keep registers)
            if (!owned) {
                const int rs = (ch - 1) & 1;
                v2f nV = {0.f, 0.f}, nSX = {0.f, 0.f}, nSY = {0.f, 0.f};
                v2f nSXM = {0.f, 0.f};
                float nsym = 0.f;
                if (inD) {
                    nV  = ld_f2(&vzS[rs][g]);
                    nSX = ld_f2(&sxzS[rs][g]);
                    nSY = ld_f2(&syzS[rs][g]);
                }
                if (haloUp)   nSXM = ld_f2(&sxzS[rs][g - NY]);
                if (haloLeft) nsym = ld_f1(&syzS[rs][g - 1]);
                V = nV; SX = nSX; SY = nSY; SXM = nSXM; symv = nsym;
            }
        }

        // stage vz into LDS buffer 0
        *(v2f*)&s_vz[0][LIDX(r, c0)] = V;
        __syncthreads();

        const int t0 = ch * 8;
        float trx[8], tryy[8];
        #pragma unroll
        for (int s = 0; s < 8; ++s) {
            const int t = t0 + s;
            float2 t2 = (t < N_STEPS) ? traj[t] : make_float2(0.f, 0.f);
            trx[s] = t2.x; tryy[s] = t2.y;
        }

        // chunk-level uniform source-skip: min dist^2 from region bbox
        bool srcNear = false;
        #pragma unroll
        for (int s = 0; s < 8; ++s) {
            const float ddx = fmaxf(fmaxf(xlo - trx[s], trx[s] - xhi), 0.0f);
            const float ddy = fmaxf(fmaxf(ylo - tryy[s], tryy[s] - yhi), 0.0f);
            if (ddx * ddx + ddy * ddy < kSRC_SKIP_D2) srcNear = true;
        }

        v2f hv[8], hs[8];
        #pragma unroll
        for (int s = 0; s < 8; ++s) {
            const int cur = s & 1, nxt = cur ^ 1;

            const v2f vp = *(const v2f*)&s_vz[cur][LIDX(r + 1, c0)];
            const v2f vm = *(const v2f*)&s_vz[cur][LIDX(r - 1, c0)];
            const float vr2 = s_vz[cur][LIDX(r, c0 + 2)];
            const float vl1 = s_vz[cur][LIDX(r, c0 - 1)];

            // forward differences (packed)
            const v2f dvx = (vp - V) * mx2;
            const v2f vsh = {V.y, vr2};
            const v2f dvy = (vsh - V) * my2;

            // own strain/sigma (packed fma)
            SX += dvx * kDT;
            SY += dvy * kDT;
            const v2f GX = SX * kMU + dvx * kETA;
            const v2f GY = SY * kMU + dvy * kETA;

            // halo strain/sigma: row above (packed) + col left (scalar)
            const v2f dxm = (V - vm) * kINV_DX;
            SXM += dxm * kDT;
            const v2f GXM = SXM * kMU + dxm * kETA;
            const float dym = (V.x - vl1) * kINV_DY;
            symv += dym * kDT;
            const float gym = kMU * symv + kETA * dym;

            // stress divergence (packed, boundary via masks)
            const v2f gsh = {gym, GY.x};
            v2f ds = (GX - GXM) * mbx2 + (GY - gsh) * mby2;

            if (srcNear) {
                const float rx  = xi - trx[s];
                const float rx2 = rx * rx;
                const v2f ry  = yy2 - tryy[s];
                const v2f arg = (ry * ry + rx2) * kNEG_INV_2SIG2;
                ds += (v2f){__expf(arg.x), __expf(arg.y)};
            }

            V = (V + ds * kDT_OVER_RHO) * damp2;

            if (s < 7) *(v2f*)&s_vz[nxt][LIDX(r, c0)] = V;

            hv[s] = V;
            const v2f g2 = GX * GX + GY * GY + kEPS;
            hs[s] = (v2f){__builtin_amdgcn_sqrtf(g2.x),
                          __builtin_amdgcn_sqrtf(g2.y)};

            if (s < 7) __syncthreads();
        }

        // state store for neighbors via LLC (skip on last chunk)
        if (owned && ch < NCHUNK - 1) {
            const int wsI = ch & 1;
            st_f2(&vzS[wsI][g],  V);
            st_f2(&sxzS[wsI][g], SX);
            st_f2(&syzS[wsI][g], SY);
        }
        // hipcc drains vmcnt before s_barrier: state stores LLC-visible here.
        __syncthreads();
        if (ch < NCHUNK - 1 && tid == 0) {
            __hip_atomic_store(&seq[bid * 4], (unsigned)(ch + 1),
                               __ATOMIC_RELAXED, __HIP_MEMORY_SCOPE_AGENT);
        }

        // history flush (plain stores, lazy writeback; overlaps next poll)
        if (owned) {
            #pragma unroll
            for (int s = 0; s < 8; ++s) {
                if (t0 + s < N_STEPS) {
                    *(v2f*)&out[(size_t)(t0 + s) * N_CELLS + g] = hv[s];
                    *(v2f*)&out[(size_t)(N_STEPS + t0 + s) * N_CELLS + g] = hs[s];
                }
            }
        }
    }
}

extern "C" void kernel_launch(void* const* d_in, const int* in_sizes, int n_in,
                              void* d_out, int out_size, void* d_ws, size_t ws_size,
                              hipStream_t stream) {
    const float2* traj = (const float2*)d_in[0];
    float* out = (float*)d_out;
    float* ws  = (float*)d_ws;
    unsigned* seq = (unsigned*)((char*)d_ws + (size_t)6 * N_CELLS * sizeof(float));

    // flags must start at 0 every launch (graph replays don't re-poison)
    hipMemsetAsync(seq, 0, NBLKS * 4 * sizeof(unsigned), stream);

    // plain launch (see note above persist_kernel)
    persist_kernel<<<dim3(NBLKS), dim3(NTHREADS), 0, stream>>>(traj, out, ws, seq);
}

// Round 15
// 191.098 us; speedup vs baseline: 1.1370x; 1.1370x over previous
//
#include <hip/hip_runtime.h>
#include <math.h>

typedef float v2f __attribute__((ext_vector_type(2)));

#define NX 256
#define NY 256
#define N_STEPS 300
#define N_CELLS (NX * NY)
#define TILE 16
#define HALO 8
#define LSTR 36              // LDS row stride in floats
#define LROWS 34             // rows -1..32
#define LIDX(rr, cc) (((rr) + 1) * LSTR + ((cc) + 2))
#define NBX 16
#define NBY 16
#define NCHUNK 38            // 38*8 = 304 >= 300; history suppressed past 299

// f32 constants (double-precision fold -> f32)
#define kINV_DX       1280.0f
#define kINV_DY       1280.0f
#define kDT           2.5e-5f
#define kMU           25000.0f
#define kETA          0.1f
#define kDT_OVER_RHO  2.5e-8f
#define kONE_MINUS_BD 0.99999975f
#define kNEG_INV_2SIG2 (-55555.5546875f)   // -1/(2*0.003^2)
#define kDX           7.8125e-4f
#define kEPS          1e-8f
#define kSRC_SKIP_D2  9.0e-4f              // (0.03 m)^2: exp(-55555*9e-4) ~ 2e-22

__device__ __forceinline__ float dprof(int k) {
    int m = min(k, NX - 1 - k);
    if (m >= 20) return 1.0f;
    float arg = 3.14159265358979f * (float)(20 - m) / 20.0f;
    return 1.0f - 0.05f * (0.5f + 0.5f * cosf(arg));
}

// LLC-coherent (agent-scope, relaxed) accessors — no cache-maintenance ops.
__device__ __forceinline__ void st_f2(float* p, v2f v) {
    union { v2f f; unsigned long long u; } x;
    x.f = v;
    __hip_atomic_store((unsigned long long*)p, x.u,
                       __ATOMIC_RELAXED, __HIP_MEMORY_SCOPE_AGENT);
}
__device__ __forceinline__ v2f ld_f2(const float* p) {
    union { unsigned long long u; v2f f; } x;
    x.u = __hip_atomic_load((const unsigned long long*)p,
                            __ATOMIC_RELAXED, __HIP_MEMORY_SCOPE_AGENT);
    return x.f;
}
__device__ __forceinline__ float ld_f1(const float* p) {
    union { unsigned u; float f; } x;
    x.u = __hip_atomic_load((const unsigned*)p,
                            __ATOMIC_RELAXED, __HIP_MEMORY_SCOPE_AGENT);
    return x.f;
}

__global__ __launch_bounds__(512, 1) void persist_kernel(
    const float2* __restrict__ traj,
    float* __restrict__ out,
    float* __restrict__ ws,
    unsigned* __restrict__ seq)      // per-block flags, stride 4 uints
{
    __shared__ float s_vz[2][LROWS * LSTR];

    float* vzS[2]  = { ws + 0 * N_CELLS, ws + 1 * N_CELLS };
    float* sxzS[2] = { ws + 2 * N_CELLS, ws + 3 * N_CELLS };
    float* syzS[2] = { ws + 4 * N_CELLS, ws + 5 * N_CELLS };

    const int tid = threadIdx.x;
    const int bid = blockIdx.x;
    const int bx  = bid & (NBX - 1), by = bid >> 4;
    const int r   = tid >> 4;            // region row, 0..31
    const int c0  = (tid & 15) << 1;     // region col base, 0,2,...,30

    const int gi  = by * TILE + r  - HALO;
    const int gj0 = bx * TILE + c0 - HALO;
    const int g   = gi * NY + gj0;

    const bool rowOK  = (gi >= 0) && (gi < NX);
    const bool colOK  = (gj0 >= 0) && (gj0 < NY);
    const bool inD    = rowOK && colOK;
    const bool haloUp   = (gi - 1 >= 0) && (gi - 1 < NX) && colOK;
    const bool haloLeft = rowOK && (gj0 - 1 >= 0);

    // boundary handling as premultiplied masks (mul-by-0 == reference zero pad)
    const float mxF  = (gi < NX - 1)      ? kINV_DX : 0.0f;
    const float myF1 = (gj0 + 1 < NY - 1) ? kINV_DY : 0.0f;
    const float mbX  = (gi > 0)           ? kINV_DX : 0.0f;
    const float mbY0 = (gj0 > 0)          ? kINV_DY : 0.0f;
    const v2f mx2  = {mxF, mxF};
    const v2f my2  = {kINV_DY, myF1};
    const v2f mbx2 = {mbX, mbX};
    const v2f mby2 = {mbY0, kINV_DY};

    const float dpx = rowOK ? dprof(gi) : 0.0f;
    const v2f damp2 = { inD ? dpx * dprof(gj0) * kONE_MINUS_BD : 0.0f,
                        inD ? dpx * dprof(gj0 + 1) * kONE_MINUS_BD : 0.0f };
    const float xi  = ((float)gi + 0.5f) * kDX;
    const v2f   yy2 = { ((float)gj0 + 0.5f) * kDX, ((float)gj0 + 1.5f) * kDX };

    const bool owned = (r >= HALO) && (r < HALO + TILE) &&
                       (c0 >= HALO) && (c0 + 1 < HALO + TILE);

    // region bbox in meters (x = rows/by, y = cols/bx) for source-skip test
    const float xlo = ((float)(by * TILE - HALO) + 0.5f) * kDX;
    const float xhi = ((float)(by * TILE + TILE + HALO - 1) + 0.5f) * kDX;
    const float ylo = ((float)(bx * TILE - HALO) + 0.5f) * kDX;
    const float yhi = ((float)(bx * TILE + TILE + HALO - 1) + 0.5f) * kDX;

    // poller lanes: first 8 threads each own one neighbor direction.
    // NOTE (R12-R14 lesson): per-thread dependency polling without the
    // post-poll block barrier races nondeterministically. The 8-poller +
    // __syncthreads structure below is load-bearing — do not "optimize".
    bool isPoller = false; int pollIdx = 0;
    if (tid < 8) {
        const int q  = tid + (tid >= 4);     // skip center of 3x3
        const int dy = q / 3 - 1, dx = q % 3 - 1;
        const int nbx_ = bx + dx, nby_ = by + dy;
        if (nbx_ >= 0 && nbx_ < NBX && nby_ >= 0 && nby_ < NBY) {
            isPoller = true;
            pollIdx = (nby_ * NBX + nbx_) * 4;
        }
    }

    // zero LDS once; pads stay zero forever
    for (int idx = tid; idx < 2 * LROWS * LSTR; idx += 512)
        ((float*)s_vz)[idx] = 0.0f;

    // persistent per-thread state
    v2f V = {0.f, 0.f}, SX = {0.f, 0.f}, SY = {0.f, 0.f}, SXM = {0.f, 0.f};
    float symv = 0.f;
    __syncthreads();

    for (int ch = 0; ch < NCHUNK; ++ch) {
        if (ch > 0) {
            // wait: all existing neighbors completed chunk ch-1 (flag >= ch)
            if (isPoller) {
                const unsigned tgt = (unsigned)ch;
                while (__hip_atomic_load(&seq[pollIdx], __ATOMIC_RELAXED,
                                         __HIP_MEMORY_SCOPE_AGENT) < tgt) {
                    __builtin_amdgcn_s_sleep(1);
                }
            }
            __syncthreads();   // poll done for all 8 dirs before anyone reads

            // halo-only reload (LLC-coherent loads; owners keep registers)
            if (!owned) {
                const int rs = (ch - 1) & 1;
                v2f nV = {0.f, 0.f}, nSX = {0.f, 0.f}, nSY = {0.f, 0.f};
                v2f nSXM = {0.f, 0.f};
                float nsym = 0.f;
                if (inD) {
                    nV  = ld_f2(&vzS[rs][g]);
                    nSX = ld_f2(&sxzS[rs][g]);
                    nSY = ld_f2(&syzS[rs][g]);
                }
                if (haloUp)   nSXM = ld_f2(&sxzS[rs][g - NY]);
                if (haloLeft) nsym = ld_f1(&syzS[rs][g - 1]);
                V = nV; SX = nSX; SY = nSY; SXM = nSXM; symv = nsym;
            }
        }

        // stage vz into LDS buffer 0
        *(v2f*)&s_vz[0][LIDX(r, c0)] = V;
        __syncthreads();

        const int t0 = ch * 8;
        float trx[8], tryy[8];
        #pragma unroll
        for (int s = 0; s < 8; ++s) {
            const int t = t0 + s;
            float2 t2 = (t < N_STEPS) ? traj[t] : make_float2(0.f, 0.f);
            trx[s] = t2.x; tryy[s] = t2.y;
        }

        // chunk-level uniform source-skip: min dist^2 from region bbox
        bool srcNear = false;
        #pragma unroll
        for (int s = 0; s < 8; ++s) {
            const float ddx = fmaxf(fmaxf(xlo - trx[s], trx[s] - xhi), 0.0f);
            const float ddy = fmaxf(fmaxf(ylo - tryy[s], tryy[s] - yhi), 0.0f);
            if (ddx * ddx + ddy * ddy < kSRC_SKIP_D2) srcNear = true;
        }

        v2f hv[8], hs[8];
        #pragma unroll
        for (int s = 0; s < 8; ++s) {
            const int cur = s & 1, nxt = cur ^ 1;

            const v2f vp = *(const v2f*)&s_vz[cur][LIDX(r + 1, c0)];
            const v2f vm = *(const v2f*)&s_vz[cur][LIDX(r - 1, c0)];
            const float vr2 = s_vz[cur][LIDX(r, c0 + 2)];
            const float vl1 = s_vz[cur][LIDX(r, c0 - 1)];

            // forward differences (packed)
            const v2f dvx = (vp - V) * mx2;
            const v2f vsh = {V.y, vr2};
            const v2f dvy = (vsh - V) * my2;

            // own strain/sigma (packed fma)
            SX += dvx * kDT;
            SY += dvy * kDT;
            const v2f GX = SX * kMU + dvx * kETA;
            const v2f GY = SY * kMU + dvy * kETA;

            // halo strain/sigma: row above (packed) + col left (scalar)
            const v2f dxm = (V - vm) * kINV_DX;
            SXM += dxm * kDT;
            const v2f GXM = SXM * kMU + dxm * kETA;
            const float dym = (V.x - vl1) * kINV_DY;
            symv += dym * kDT;
            const float gym = kMU * symv + kETA * dym;

            // stress divergence (packed, boundary via masks)
            const v2f gsh = {gym, GY.x};
            v2f ds = (GX - GXM) * mbx2 + (GY - gsh) * mby2;

            if (srcNear) {
                const float rx  = xi - trx[s];
                const float rx2 = rx * rx;
                const v2f ry  = yy2 - tryy[s];
                const v2f arg = (ry * ry + rx2) * kNEG_INV_2SIG2;
                ds += (v2f){__expf(arg.x), __expf(arg.y)};
            }

            V = (V + ds * kDT_OVER_RHO) * damp2;

            if (s < 7) *(v2f*)&s_vz[nxt][LIDX(r, c0)] = V;

            hv[s] = V;
            const v2f g2 = GX * GX + GY * GY + kEPS;
            hs[s] = (v2f){__builtin_amdgcn_sqrtf(g2.x),
                          __builtin_amdgcn_sqrtf(g2.y)};

            if (s < 7) __syncthreads();
        }

        // state store for neighbors via LLC (skip on last chunk)
        if (owned && ch < NCHUNK - 1) {
            const int wsI = ch & 1;
            st_f2(&vzS[wsI][g],  V);
            st_f2(&sxzS[wsI][g], SX);
            st_f2(&syzS[wsI][g], SY);
        }
        // hipcc drains vmcnt before s_barrier: state stores LLC-visible here.
        __syncthreads();
        if (ch < NCHUNK - 1 && tid == 0) {
            __hip_atomic_store(&seq[bid * 4], (unsigned)(ch + 1),
                               __ATOMIC_RELAXED, __HIP_MEMORY_SCOPE_AGENT);
        }

        // history flush (plain stores, lazy writeback; overlaps next poll)
        if (owned) {
            #pragma unroll
            for (int s = 0; s < 8; ++s) {
                if (t0 + s < N_STEPS) {
                    *(v2f*)&out[(size_t)(t0 + s) * N_CELLS + g] = hv[s];
                    *(v2f*)&out[(size_t)(N_STEPS + t0 + s) * N_CELLS + g] = hs[s];
                }
            }
        }
    }
}

extern "C" void kernel_launch(void* const* d_in, const int* in_sizes, int n_in,
                              void* d_out, int out_size, void* d_ws, size_t ws_size,
                              hipStream_t stream) {
    const float2* traj = (const float2*)d_in[0];
    float* out = (float*)d_out;
    float* ws  = (float*)d_ws;
    unsigned* seq = (unsigned*)((char*)d_ws + (size_t)6 * N_CELLS * sizeof(float));

    // flags must start at 0 on every launch (graph replays don't re-poison)
    hipMemsetAsync(seq, 0, NBX * NBY * 4 * sizeof(unsigned), stream);

    void* args[] = { (void*)&traj, (void*)&out, (void*)&ws, (void*)&seq };
    hipLaunchCooperativeKernel((const void*)persist_kernel,
                               dim3(NBX * NBY), dim3(512), args, 0, stream);
}